// Round 13
// baseline (60.466 us; speedup 1.0000x reference)
//
#include <hip/hip_runtime.h>

#define D 1024
#define T 2048
#define BATCH 4

typedef float nfloat4 __attribute__((ext_vector_type(4)));  // native vec for nontemporal builtin

// workspace float offsets
#define WS_PARTW 0        // [16][1024] : Wk colsum partials (esub-major)
#define WS_BBAR  16384    // 1 float    : mean(bk)
#define WS_Z     16388    // 4 floats   : 1/Z[b]
#define WS_ZP    16640    // 1024       : per-block Z partials
#define WS_O     21760    // 4096       : o[b][d] PRE-norm, atomic-accumulated (16B aligned)
#define WS_PART  32768    // [4][256][1024] : per-block u partials (4 MB)

// ---- K1: Wk colsum partials (256 blocks), bbar (256), zero o (257)
__global__ void __launch_bounds__(256) k_prep(const float4* __restrict__ Wk4,
                                              const float* __restrict__ bk,
                                              float* __restrict__ ws) {
    __shared__ float4 sm[16][17];
    __shared__ float red[256];
    const int bid = blockIdx.x, tid = threadIdx.x;
    if (bid < 256) {
        const int esub = bid & 15, dchunk = bid >> 4;  // e-range 64, d4-range 16
        const int fc = tid & 15, eg = tid >> 4;
        const int d4 = dchunk * 16 + fc;               // 0..255
        float4 s = make_float4(0.f, 0.f, 0.f, 0.f);
        #pragma unroll
        for (int k = 0; k < 4; ++k) {
            const int e = esub * 64 + k * 16 + eg;     // 0..1023
            const float4 v = Wk4[e * 256 + d4];
            s.x += v.x; s.y += v.y; s.z += v.z; s.w += v.w;
        }
        sm[eg][fc] = s;
        __syncthreads();
        if (tid < 16) {
            float4 t = make_float4(0.f, 0.f, 0.f, 0.f);
            #pragma unroll
            for (int g = 0; g < 16; ++g) {
                const float4 v = sm[g][tid];
                t.x += v.x; t.y += v.y; t.z += v.z; t.w += v.w;
            }
            ((float4*)(ws + WS_PARTW))[esub * 256 + dchunk * 16 + tid] = t;
        }
    } else if (bid == 256) {
        red[tid] = bk[tid] + bk[tid + 256] + bk[tid + 512] + bk[tid + 768];
        __syncthreads();
        for (int off = 128; off > 0; off >>= 1) {
            if (tid < off) red[tid] += red[tid + off];
            __syncthreads();
        }
        if (tid == 0) ws[WS_BBAR] = red[0] * (1.0f / D);
    } else {
        float4* o4 = (float4*)(ws + WS_O);             // re-zero o every call (atomic target)
        #pragma unroll
        for (int k = 0; k < 4; ++k)
            o4[k * 256 + tid] = make_float4(0.f, 0.f, 0.f, 0.f);
    }
}

// ---- K2: single pass over x. 1024 blocks x 8 rows upfront, one sync, partials.
__global__ void __launch_bounds__(256) k_pass(const float4* __restrict__ x4,
                                              float* __restrict__ ws) {
    __shared__ float lds[4][8];
    const int tid = threadIdx.x, lane = tid & 63, w = tid >> 6;
    const int bid = blockIdx.x;
    const int b = bid >> 8, tc = bid & 255;          // 256 blocks/batch, 8 rows each

    // wbar[tid] (float4) from the 16 e-subrange partials (L2-hot, 16 KB)
    const float4* pw = (const float4*)(ws + WS_PARTW);
    float4 wq = make_float4(0.f, 0.f, 0.f, 0.f);
    #pragma unroll
    for (int s = 0; s < 16; ++s) {
        const float4 v = pw[s * 256 + tid];
        wq.x += v.x; wq.y += v.y; wq.z += v.z; wq.w += v.w;
    }
    wq.x *= (1.0f / D); wq.y *= (1.0f / D);
    wq.z *= (1.0f / D); wq.w *= (1.0f / D);
    const float bbar = ws[WS_BBAR];

    // phase 1: load 8 rows (independent -> deep ILP), dot partials
    const float4* xr = x4 + (size_t)(b * T + tc * 8) * 256;
    float4 xv[8];
    #pragma unroll
    for (int j = 0; j < 8; ++j) xv[j] = xr[j * 256 + tid];
    float p[8];
    #pragma unroll
    for (int j = 0; j < 8; ++j)
        p[j] = xv[j].x * wq.x + xv[j].y * wq.y + xv[j].z * wq.z + xv[j].w * wq.w;

    // phase 2: batched block reduction, one sync
    #pragma unroll
    for (int off = 32; off > 0; off >>= 1) {
        #pragma unroll
        for (int j = 0; j < 8; ++j) p[j] += __shfl_down(p[j], off);
    }
    if (lane == 0) {
        #pragma unroll
        for (int j = 0; j < 8; ++j) lds[w][j] = p[j];
    }
    __syncthreads();

    float4 acc = make_float4(0.f, 0.f, 0.f, 0.f);
    float zs = 0.f;
    #pragma unroll
    for (int j = 0; j < 8; ++j) {
        const float km = lds[0][j] + lds[1][j] + lds[2][j] + lds[3][j] + bbar;
        const float e = expf(cosf(km));  // cos in [-1,1] -> exp in (0.36,2.72): no max needed
        zs += e;
        acc.x += e * xv[j].x; acc.y += e * xv[j].y;
        acc.z += e * xv[j].z; acc.w += e * xv[j].w;
    }

    ((float4*)(ws + WS_PART))[(size_t)bid * 256 + tid] = acc;  // [b][tc][d4]
    if (tid == 0) ws[WS_ZP + bid] = zs;
}

// ---- K3: fused reduce+proj. 64 blocks (b,dc). Phase 1: u_chunk[64] = sum of
// 256 partials for this d-chunk (deterministic). Phase 2: po[d] += u_chunk .
// Wv[d, chunk] for all 1024 d via 16-lane groups, atomicAdd into o (16
// writers/word -> light). Also Z: block (b,0) writes 1/Z[b].
__global__ void __launch_bounds__(256) k_redproj(const float4* __restrict__ Wv4,
                                                 float* __restrict__ ws) {
    __shared__ float4 sm[16][17];
    __shared__ float4 uc[16];
    const int bid = blockIdx.x, tid = threadIdx.x;
    const int b = bid >> 4, dc = bid & 15;           // 16 chunk-blocks per batch
    const int dl = tid & 15, pg = tid >> 4;
    const float4* pb = (const float4*)(ws + WS_PART) + (size_t)b * 65536;
    float4 s = make_float4(0.f, 0.f, 0.f, 0.f);
    #pragma unroll
    for (int k = 0; k < 16; ++k) {
        const float4 v = pb[(pg * 16 + k) * 256 + dc * 16 + dl];
        s.x += v.x; s.y += v.y; s.z += v.z; s.w += v.w;
    }
    sm[pg][dl] = s;
    __syncthreads();
    if (tid < 16) {
        float4 t = make_float4(0.f, 0.f, 0.f, 0.f);
        #pragma unroll
        for (int g = 0; g < 16; ++g) {
            const float4 v = sm[g][tid];
            t.x += v.x; t.y += v.y; t.z += v.z; t.w += v.w;
        }
        uc[tid] = t;                                  // u[b, dc*64 .. dc*64+63]
    }
    __syncthreads();

    // phase 2: each 16-lane group handles one d per iteration
    const int k  = tid & 15;                          // float4 idx within chunk
    const int dg = (tid >> 4) & 3;
    const int w  = tid >> 6;
    const float4 u = uc[k];                           // LDS broadcast
    float* o = ws + WS_O + b * D;
    for (int di = 0; di < 64; ++di) {
        const int d = di * 16 + w * 4 + dg;
        const float4 wv = Wv4[d * 256 + dc * 16 + k]; // 256B-coalesced per group
        float sd = u.x * wv.x + u.y * wv.y + u.z * wv.z + u.w * wv.w;
        sd += __shfl_xor(sd, 1);
        sd += __shfl_xor(sd, 2);
        sd += __shfl_xor(sd, 4);
        sd += __shfl_xor(sd, 8);
        if (k == 0) atomicAdd(o + d, sd);
    }

    // Z: single wave, no barriers (divergence-safe)
    if (dc == 0 && tid < 64) {
        float z = ws[WS_ZP + b * 256 + tid]       + ws[WS_ZP + b * 256 + tid + 64] +
                  ws[WS_ZP + b * 256 + tid + 128] + ws[WS_ZP + b * 256 + tid + 192];
        #pragma unroll
        for (int off = 32; off > 0; off >>= 1) z += __shfl_down(z, off);
        if (tid == 0) ws[WS_Z + b] = 1.0f / z;
    }
}

// ---- K4: out[b,t,d] = o[b,d]*invZ[b] + bv[d]  (32 MiB streaming broadcast)
__global__ void __launch_bounds__(256) k_bcast(const float* __restrict__ ws,
                                               const float* __restrict__ bv,
                                               nfloat4* __restrict__ out4) {
    const nfloat4* o4  = (const nfloat4*)(ws + WS_O);
    const nfloat4* bv4 = (const nfloat4*)bv;
    const int idx = blockIdx.x * 256 + threadIdx.x;   // 0..1048575
    #pragma unroll
    for (int i = 0; i < 2; ++i) {
        const int f = idx + i * 1048576;              // 2^21 float4 total
        const int b = f >> 19, d4 = f & 255;
        const float invZ = ws[WS_Z + b];
        const nfloat4 v = o4[(b << 8) + d4] * invZ + bv4[d4];
        __builtin_nontemporal_store(v, &out4[f]);
    }
}

extern "C" void kernel_launch(void* const* d_in, const int* in_sizes, int n_in,
                              void* d_out, int out_size, void* d_ws, size_t ws_size,
                              hipStream_t stream) {
    const float* x  = (const float*)d_in[0];
    // d_in[1] = Wq, d_in[2] = bq : dead code in the reference
    const float* Wk = (const float*)d_in[3];
    const float* bk = (const float*)d_in[4];
    const float* Wv = (const float*)d_in[5];
    const float* bv = (const float*)d_in[6];
    float* ws  = (float*)d_ws;
    float* out = (float*)d_out;

    k_prep   <<<258, 256, 0, stream>>>((const float4*)Wk, bk, ws);
    k_pass   <<<1024, 256, 0, stream>>>((const float4*)x, ws);
    k_redproj<<<64, 256, 0, stream>>>((const float4*)Wv, ws);
    k_bcast  <<<4096, 256, 0, stream>>>(ws, bv, (nfloat4*)out);
}

// Round 14
// 33.153 us; speedup vs baseline: 1.8238x; 1.8238x over previous
//
#include <hip/hip_runtime.h>

#define D 1024
#define T 2048
#define BATCH 4

typedef float nfloat4 __attribute__((ext_vector_type(4)));  // native vec for nontemporal builtin

// workspace float offsets
#define WS_WBAR  0        // 1024 : mean_e Wk[e,d]
#define WS_BBAR  1024     // 1    : mean(bk)
#define WS_Z     1028     // 4    : Z[b]
#define WS_ZP    1088     // 1024 : per-block Z partials
#define WS_U     2112     // 4096 : u[b][d] (16B aligned)
#define WS_O     6208     // 4096 : o[b][d] (16B aligned)
#define WS_PART  16384    // [4][256][1024] : per-block u partials (4 MB)

// ---- K1: wbar direct (blocks 0..15), bbar+zero Z (16)
__global__ void __launch_bounds__(256) k_prep(const float4* __restrict__ Wk4,
                                              const float* __restrict__ bk,
                                              float* __restrict__ ws) {
    __shared__ float4 sm[16][17];
    __shared__ float red[256];
    const int bid = blockIdx.x, tid = threadIdx.x;
    if (bid < 16) {
        const int fc = tid & 15, eg = tid >> 4;      // 16 d4-cols x 16 e-groups
        const int d4 = bid * 16 + fc;                // 0..255  (D/4 = 256 cols)
        float4 s = make_float4(0.f, 0.f, 0.f, 0.f);
        #pragma unroll 8
        for (int k = 0; k < 64; ++k) {               // e = eg + 16*k : 0..1023
            const float4 v = Wk4[(eg + k * 16) * 256 + d4];
            s.x += v.x; s.y += v.y; s.z += v.z; s.w += v.w;
        }
        sm[eg][fc] = s;
        __syncthreads();
        if (tid < 16) {
            float4 t = make_float4(0.f, 0.f, 0.f, 0.f);
            #pragma unroll
            for (int g = 0; g < 16; ++g) {
                const float4 v = sm[g][tid];
                t.x += v.x; t.y += v.y; t.z += v.z; t.w += v.w;
            }
            t.x *= (1.0f / D); t.y *= (1.0f / D);
            t.z *= (1.0f / D); t.w *= (1.0f / D);
            ((float4*)(ws + WS_WBAR))[bid * 16 + tid] = t;   // 0..255 float4
        }
    } else {
        red[tid] = bk[tid] + bk[tid + 256] + bk[tid + 512] + bk[tid + 768];
        __syncthreads();
        for (int off = 128; off > 0; off >>= 1) {
            if (tid < off) red[tid] += red[tid + off];
            __syncthreads();
        }
        if (tid == 0) ws[WS_BBAR] = red[0] * (1.0f / D);
        if (tid < 4) ws[WS_Z + tid] = 0.f;
    }
}

// ---- K2: single pass over x. 1024 blocks x 8 rows upfront, one sync, partials.
__global__ void __launch_bounds__(256) k_pass(const float4* __restrict__ x4,
                                              float* __restrict__ ws) {
    __shared__ float lds[4][8];
    const int tid = threadIdx.x, lane = tid & 63, w = tid >> 6;
    const int bid = blockIdx.x;
    const int b = bid >> 8, tc = bid & 255;          // 256 blocks/batch, 8 rows each

    const float4 wq = ((const float4*)(ws + WS_WBAR))[tid];   // 4 KB, L2-hot
    const float bbar = ws[WS_BBAR];

    // phase 1: load 8 rows (independent -> deep ILP), dot partials
    const float4* xr = x4 + (size_t)(b * T + tc * 8) * 256;
    float4 xv[8];
    #pragma unroll
    for (int j = 0; j < 8; ++j) xv[j] = xr[j * 256 + tid];
    float p[8];
    #pragma unroll
    for (int j = 0; j < 8; ++j)
        p[j] = xv[j].x * wq.x + xv[j].y * wq.y + xv[j].z * wq.z + xv[j].w * wq.w;

    // phase 2: batched block reduction, one sync
    #pragma unroll
    for (int off = 32; off > 0; off >>= 1) {
        #pragma unroll
        for (int j = 0; j < 8; ++j) p[j] += __shfl_down(p[j], off);
    }
    if (lane == 0) {
        #pragma unroll
        for (int j = 0; j < 8; ++j) lds[w][j] = p[j];
    }
    __syncthreads();

    float4 acc = make_float4(0.f, 0.f, 0.f, 0.f);
    float zs = 0.f;
    #pragma unroll
    for (int j = 0; j < 8; ++j) {
        const float km = lds[0][j] + lds[1][j] + lds[2][j] + lds[3][j] + bbar;
        const float e = expf(cosf(km));  // cos in [-1,1] -> exp in (0.36,2.72): no max needed
        zs += e;
        acc.x += e * xv[j].x; acc.y += e * xv[j].y;
        acc.z += e * xv[j].z; acc.w += e * xv[j].w;
    }

    ((float4*)(ws + WS_PART))[(size_t)bid * 256 + tid] = acc;  // [b][tc][d4]
    if (tid == 0) ws[WS_ZP + bid] = zs;
}

// ---- K3: u[b][:] = sum of 256 partials (deterministic); Z[b] = sum ZP
__global__ void __launch_bounds__(256) k_reduce(float* __restrict__ ws) {
    __shared__ float4 sm[16][17];
    __shared__ float zr[4];
    const int bid = blockIdx.x, tid = threadIdx.x;
    const int b = bid >> 4, dc = bid & 15;           // 16 blocks per batch
    const int dl = tid & 15, pg = tid >> 4;
    const float4* pb = (const float4*)(ws + WS_PART) + (size_t)b * 65536;
    float4 s = make_float4(0.f, 0.f, 0.f, 0.f);
    #pragma unroll
    for (int k = 0; k < 16; ++k) {
        const float4 v = pb[(pg * 16 + k) * 256 + dc * 16 + dl];
        s.x += v.x; s.y += v.y; s.z += v.z; s.w += v.w;
    }
    sm[pg][dl] = s;
    __syncthreads();
    if (tid < 16) {
        float4 t = make_float4(0.f, 0.f, 0.f, 0.f);
        #pragma unroll
        for (int g = 0; g < 16; ++g) {
            const float4 v = sm[g][tid];
            t.x += v.x; t.y += v.y; t.z += v.z; t.w += v.w;
        }
        ((float4*)(ws + WS_U))[b * 256 + dc * 16 + tid] = t;
    }
    if (dc == 0) {                      // block-uniform branch: barrier inside is safe
        float z = ws[WS_ZP + b * 256 + tid];
        #pragma unroll
        for (int off = 32; off > 0; off >>= 1) z += __shfl_down(z, off);
        if ((tid & 63) == 0) zr[tid >> 6] = z;
        __syncthreads();
        if (tid == 0) ws[WS_Z + b] = zr[0] + zr[1] + zr[2] + zr[3];
    }
}

// ---- K4: o[b,d] = (u[b,:].Wv[d,:]) / Z[b] + bv[d] ; one block per d
__global__ void __launch_bounds__(256) k_proj(const float4* __restrict__ Wv4,
                                              float* __restrict__ ws,
                                              const float* __restrict__ bv) {
    __shared__ float lds[4][4];
    const int tid = threadIdx.x, lane = tid & 63, w = tid >> 6;
    const int d = blockIdx.x;
    const float4 wvv = Wv4[d * 256 + tid];
    const float4* u4 = (const float4*)(ws + WS_U);
    float a[BATCH];
    #pragma unroll
    for (int b = 0; b < BATCH; ++b) {
        const float4 u = u4[b * 256 + tid];
        a[b] = wvv.x * u.x + wvv.y * u.y + wvv.z * u.z + wvv.w * u.w;
    }
    #pragma unroll
    for (int off = 32; off > 0; off >>= 1) {
        #pragma unroll
        for (int b = 0; b < BATCH; ++b) a[b] += __shfl_down(a[b], off);
    }
    if (lane == 0) {
        #pragma unroll
        for (int b = 0; b < BATCH; ++b) lds[w][b] = a[b];
    }
    __syncthreads();
    if (tid == 0) {
        const float bb = bv[d];
        #pragma unroll
        for (int b = 0; b < BATCH; ++b) {
            const float s = lds[0][b] + lds[1][b] + lds[2][b] + lds[3][b];
            ws[WS_O + b * D + d] = s / ws[WS_Z + b] + bb;
        }
    }
}

// ---- K5: out[b,t,d] = o[b,d]  (32 MiB streaming broadcast write)
__global__ void __launch_bounds__(256) k_bcast(const float* __restrict__ ws,
                                               nfloat4* __restrict__ out4) {
    const nfloat4* o4 = (const nfloat4*)(ws + WS_O);
    const int idx = blockIdx.x * 256 + threadIdx.x;   // 0..1048575
    #pragma unroll
    for (int i = 0; i < 2; ++i) {
        const int f = idx + i * 1048576;              // 2^21 float4 total
        const nfloat4 v = o4[((f >> 19) << 8) + (f & 255)];
        __builtin_nontemporal_store(v, &out4[f]);
    }
}

extern "C" void kernel_launch(void* const* d_in, const int* in_sizes, int n_in,
                              void* d_out, int out_size, void* d_ws, size_t ws_size,
                              hipStream_t stream) {
    const float* x  = (const float*)d_in[0];
    // d_in[1] = Wq, d_in[2] = bq : dead code in the reference
    const float* Wk = (const float*)d_in[3];
    const float* bk = (const float*)d_in[4];
    const float* Wv = (const float*)d_in[5];
    const float* bv = (const float*)d_in[6];
    float* ws  = (float*)d_ws;
    float* out = (float*)d_out;

    k_prep  <<<17, 256, 0, stream>>>((const float4*)Wk, bk, ws);
    k_pass  <<<1024, 256, 0, stream>>>((const float4*)x, ws);
    k_reduce<<<64, 256, 0, stream>>>(ws);
    k_proj  <<<1024, 256, 0, stream>>>((const float4*)Wv, ws, bv);
    k_bcast <<<4096, 256, 0, stream>>>(ws, (nfloat4*)out);
}